// Round 8
// baseline (155.143 us; speedup 1.0000x reference)
//
#include <hip/hip_runtime.h>

typedef unsigned int uint;
typedef unsigned short ushort;
typedef __attribute__((ext_vector_type(8))) short short8;   // 8 bf16
typedef __attribute__((ext_vector_type(4))) float f32x4;

#define NSH   100
#define NPRIM 8
#define NAOC  280
#define NAOS  260
#define NATOM 20
#define KP    288
#define NKB   9
#define MT    32            // points per block
#define NCOLP 272
#define BCH   (32 * NCOLP)  // ushorts per chunk image (8704)
#define RSQRT3 0.57735026918962576f
#define LOG2E  1.4426950408889634f
#define EPS   276           // epilogue row stride (floats)
#define RSTRIDE 33          // sRad row stride (floats) — bank de-phase

// LDS byte offsets (main pool; epilogue reuses from 0)
#define O_RAD   0        // 100*33*4 = 13200
#define O_ZETA  13200    // 3200
#define O_COEF  16400    // 3200
#define O_CEN   19600    // 20 * float4 = 320
#define O_CX    19920    // 128
#define O_CY    20048    // 128
#define O_CZ    20176    // 128
#define O_NORMF 20304    // 1152
#define O_META  21456    // 1152 -> 22608
#define POOLSZ  (MT * EPS * 4)   // 35328 (epilogue dominates)

__device__ __forceinline__ ushort bf16_rne(float x) {
    uint u = __float_as_uint(x);
    return (ushort)((u + 0x7FFFu + ((u >> 16) & 1u)) >> 16);
}
__device__ __forceinline__ float bf16_to_f(ushort h) {
    return __uint_as_float(((uint)h) << 16);
}
__device__ __forceinline__ uint cvt_pk_bf16(float a, float b) {
    uint r;
    asm("v_cvt_pk_bf16_f32 %0, %1, %2" : "=v"(r) : "v"(a), "v"(b));
    return r;
}

__device__ __forceinline__ int calc_meta(int k, float& anorm) {
    int shell = 0, atom = 0, s1 = 0, s2 = 0;
    anorm = 1.0f;
    if (k < 40) {
        atom = k >> 1; shell = 5 * atom + (k & 1);
    } else if (k < 160) {
        int i = k - 40; int ip = i / 3; int c = i - 3 * ip;
        atom = ip >> 1; shell = 5 * atom + 2 + (ip & 1); s1 = 1 + c;
    } else if (k < NAOC) {
        int i = k - 160; atom = i / 6; shell = 5 * atom + 4; int c = i - 6 * atom;
        if      (c == 0) { s1 = 1; s2 = 1; }
        else if (c == 1) { s1 = 1; s2 = 2; }
        else if (c == 2) { s1 = 1; s2 = 3; }
        else if (c == 3) { s1 = 2; s2 = 2; }
        else if (c == 4) { s1 = 2; s2 = 3; }
        else             { s1 = 3; s2 = 3; }
        if (c == 0 || c == 3 || c == 5) anorm = RSQRT3;
    }
    return shell | (atom << 7) | (s1 << 12) | (s2 << 14);
}

// ---- prep: split cart2sph to bf16 hi/lo frag image + meta/normf tables ----
__global__ void prep_b(const float* __restrict__ c2s, const float* __restrict__ norm,
                       ushort* __restrict__ wsHi, ushort* __restrict__ wsLo,
                       int* __restrict__ wsMeta, float* __restrict__ wsNorm) {
    if (blockIdx.x == 0) {
        for (int k = threadIdx.x; k < KP; k += 256) {
            float an;
            int m = calc_meta(k, an);
            wsMeta[k] = m;
            wsNorm[k] = (k < NAOC ? norm[k] : 0.0f) * an;
        }
    }
    int id = blockIdx.x * 256 + threadIdx.x;
    if (id >= KP * NCOLP) return;
    int k = id / NCOLP, col = id % NCOLP;
    float v = (k < NAOC && col < NAOS) ? c2s[k * NAOS + col] : 0.0f;
    ushort hi = bf16_rne(v);
    ushort lo = bf16_rne(v - bf16_to_f(hi));
    int off = (k >> 5) * BCH +
              (((col >> 4) * 4 + ((k & 31) >> 3)) * 16 + (col & 15)) * 8 + (k & 7);
    wsHi[off] = hi;
    wsLo[off] = lo;
}

template <bool USEWS>
__global__ __launch_bounds__(256, 4) void gto_mfma(
    const float* __restrict__ coords, const float* __restrict__ centers,
    const float* __restrict__ zetas, const float* __restrict__ coeffs,
    const float* __restrict__ norm, const float* __restrict__ c2s,
    const ushort* __restrict__ wsHi, const ushort* __restrict__ wsLo,
    const int* __restrict__ wsMeta, const float* __restrict__ wsNorm,
    float* __restrict__ out, int n)
{
    __shared__ __align__(16) char smem[POOLSZ];
    float*  sRad  = (float*)(smem + O_RAD);
    float*  sZeta = (float*)(smem + O_ZETA);
    float*  sCoef = (float*)(smem + O_COEF);
    float4* sCen4 = (float4*)(smem + O_CEN);
    float*  sCx   = (float*)(smem + O_CX);
    float*  sCy   = (float*)(smem + O_CY);
    float*  sCz   = (float*)(smem + O_CZ);
    float*  sNormF= (float*)(smem + O_NORMF);
    int*    sMeta = (int*)(smem + O_META);

    const int t = threadIdx.x, lane = t & 63, w = t >> 6;
    const int lr = lane & 15, lg4 = lane >> 4;
    const int P0 = blockIdx.x * MT;

    // ---- stage constants ----
    for (int i = t; i < NSH * NPRIM; i += 256) {
        sZeta[i] = zetas[i] * LOG2E;           // pre-fold log2e for v_exp_f32
        sCoef[i] = coeffs[i];
    }
    if (t < NATOM)
        sCen4[t] = make_float4(centers[3 * t], centers[3 * t + 1], centers[3 * t + 2], 0.0f);
    if (t < MT * 3) {
        int gi = P0 * 3 + t;
        float v = (gi < 3 * n) ? coords[gi] : 0.0f;
        int p = t / 3, c = t - 3 * (t / 3);
        if (c == 0) sCx[p] = v; else if (c == 1) sCy[p] = v; else sCz[p] = v;
    }
    if (USEWS) {
        for (int i = t; i < KP; i += 256) { sMeta[i] = wsMeta[i]; sNormF[i] = wsNorm[i]; }
    } else {
        for (int k = t; k < KP; k += 256) {
            float an;
            sMeta[k] = calc_meta(k, an);
            sNormF[k] = (k < NAOC ? norm[k] : 0.0f) * an;
        }
    }
    __syncthreads();

    // ---- radial table rad[shell][point], stride RSTRIDE ----
    #pragma unroll 1
    for (int it = 0; it < (NSH * MT + 255) / 256; ++it) {
        int id = it * 256 + t;
        if (id < NSH * MT) {
            int s = id >> 5, p = id & 31;
            int a = s / 5;
            float4 ca = sCen4[a];
            float dx = sCx[p] - ca.x;
            float dy = sCy[p] - ca.y;
            float dz = sCz[p] - ca.z;
            float r2 = dx * dx + dy * dy + dz * dz;
            float4 z0 = *(const float4*)&sZeta[s * NPRIM];
            float4 z1 = *(const float4*)&sZeta[s * NPRIM + 4];
            float4 c0 = *(const float4*)&sCoef[s * NPRIM];
            float4 c1 = *(const float4*)&sCoef[s * NPRIM + 4];
            float rad = c0.x * __builtin_amdgcn_exp2f(-z0.x * r2);
            rad += c0.y * __builtin_amdgcn_exp2f(-z0.y * r2);
            rad += c0.z * __builtin_amdgcn_exp2f(-z0.z * r2);
            rad += c0.w * __builtin_amdgcn_exp2f(-z0.w * r2);
            rad += c1.x * __builtin_amdgcn_exp2f(-z1.x * r2);
            rad += c1.y * __builtin_amdgcn_exp2f(-z1.y * r2);
            rad += c1.z * __builtin_amdgcn_exp2f(-z1.z * r2);
            rad += c1.w * __builtin_amdgcn_exp2f(-z1.w * r2);
            sRad[s * RSTRIDE + p] = rad;
        }
    }
    __syncthreads();   // sRad ready — LAST barrier before epilogue

    // per-lane point coords for the two M-tiles (p = mt*16 + lr)
    const float cx0 = sCx[lr],      cy0 = sCy[lr],      cz0 = sCz[lr];
    const float cx1 = sCx[16 + lr], cy1 = sCy[16 + lr], cz1 = sCz[16 + lr];

    f32x4 acc[5][2];
    #pragma unroll
    for (int i = 0; i < 5; ++i)
        #pragma unroll
        for (int mt = 0; mt < 2; ++mt)
            acc[i][mt] = (f32x4){0.0f, 0.0f, 0.0f, 0.0f};

    union U4 { uint u[4]; short8 s; };

    #pragma unroll 1
    for (int kb = 0; kb < NKB; ++kb) {
        // ---- A-fragments fully in registers (no barriers, no LDS bufs) ----
        // lane (lr, lg4): rows p = mt*16+lr, k = kb*32 + lg4*8 + j
        const int k0 = kb * 32 + lg4 * 8;
        int4   m4a = *(const int4*)&sMeta[k0];
        int4   m4b = *(const int4*)&sMeta[k0 + 4];
        float4 n4a = *(const float4*)&sNormF[k0];
        float4 n4b = *(const float4*)&sNormF[k0 + 4];
        const int   mk[8] = {m4a.x, m4a.y, m4a.z, m4a.w, m4b.x, m4b.y, m4b.z, m4b.w};
        const float nf[8] = {n4a.x, n4a.y, n4a.z, n4a.w, n4b.x, n4b.y, n4b.z, n4b.w};

        short8 aH[2], aL[2];
        #pragma unroll
        for (int mt = 0; mt < 2; ++mt) {
            const float cxp = mt ? cx1 : cx0;
            const float cyp = mt ? cy1 : cy0;
            const float czp = mt ? cz1 : cz0;
            const int   p   = mt * 16 + lr;
            U4 uh, ul;
            #pragma unroll
            for (int jp = 0; jp < 4; ++jp) {
                float v2[2];
                #pragma unroll
                for (int h = 0; h < 2; ++h) {
                    const int j = jp * 2 + h;
                    int meta = mk[j];
                    int s = meta & 127, a = (meta >> 7) & 31;
                    int s1 = (meta >> 12) & 3, s2 = (meta >> 14) & 3;
                    float4 ca = sCen4[a];
                    float dx = cxp - ca.x, dy = cyp - ca.y, dz = czp - ca.z;
                    float m1 = (s1 == 0) ? 1.0f : ((s1 == 1) ? dx : ((s1 == 2) ? dy : dz));
                    float m2 = (s2 == 0) ? 1.0f : ((s2 == 1) ? dx : ((s2 == 2) ? dy : dz));
                    v2[h] = sRad[s * RSTRIDE + p] * (m1 * m2) * nf[j];
                }
                uint hp = cvt_pk_bf16(v2[0], v2[1]);
                float r0 = v2[0] - __uint_as_float(hp << 16);
                float r1 = v2[1] - __uint_as_float(hp & 0xffff0000u);
                uh.u[jp] = hp;
                ul.u[jp] = cvt_pk_bf16(r0, r1);
            }
            aH[mt] = uh.s;
            aL[mt] = ul.s;
        }

        // ---- B loads + MFMAs (per-wave tiles, free-running) ----
        #pragma unroll
        for (int i = 0; i < 5; ++i) {
            if (i < 4 || w == 0) {
                int nt = (i == 4) ? 16 : (w * 4 + i);
                short8 bh, bl;
                if (USEWS) {
                    bh = *(const short8*)(wsHi + (size_t)kb * BCH + (nt * 64 + lane) * 8);
                    bl = *(const short8*)(wsLo + (size_t)kb * BCH + (nt * 64 + lane) * 8);
                } else {
                    #pragma unroll
                    for (int j = 0; j < 8; ++j) {
                        int k = kb * 32 + lg4 * 8 + j;
                        int col = nt * 16 + lr;
                        float v = (k < NAOC && col < NAOS) ? c2s[k * NAOS + col] : 0.0f;
                        ushort hi = bf16_rne(v);
                        bh[j] = (short)hi;
                        bl[j] = (short)bf16_rne(v - bf16_to_f(hi));
                    }
                }
                #pragma unroll
                for (int mt = 0; mt < 2; ++mt)
                    acc[i][mt] = __builtin_amdgcn_mfma_f32_16x16x32_bf16(aH[mt], bh, acc[i][mt], 0, 0, 0);
                #pragma unroll
                for (int mt = 0; mt < 2; ++mt)
                    acc[i][mt] = __builtin_amdgcn_mfma_f32_16x16x32_bf16(aH[mt], bl, acc[i][mt], 0, 0, 0);
                #pragma unroll
                for (int mt = 0; mt < 2; ++mt)
                    acc[i][mt] = __builtin_amdgcn_mfma_f32_16x16x32_bf16(aL[mt], bh, acc[i][mt], 0, 0, 0);
            }
        }
    }

    // ---- epilogue: acc -> LDS [32][EPS] -> coalesced row stores ----
    __syncthreads();
    float* ep = (float*)smem;
    #pragma unroll
    for (int i = 0; i < 5; ++i) {
        if (i < 4 || w == 0) {
            int nt = (i == 4) ? 16 : (w * 4 + i);
            int col = nt * 16 + lr;
            #pragma unroll
            for (int mt = 0; mt < 2; ++mt)
                #pragma unroll
                for (int r = 0; r < 4; ++r)
                    ep[(mt * 16 + lg4 * 4 + r) * EPS + col] = acc[i][mt][r];
        }
    }
    __syncthreads();

    for (int row = w; row < MT; row += 4) {
        int P = P0 + row;
        if (P < n)
            *(float4*)&out[(size_t)P * NAOS + lane * 4] = *(const float4*)&ep[row * EPS + lane * 4];
    }
    if (w == 1 && lane < MT) {
        int P = P0 + lane;
        if (P < n)
            *(float4*)&out[(size_t)P * NAOS + 256] = *(const float4*)&ep[lane * EPS + 256];
    }
}

extern "C" void kernel_launch(void* const* d_in, const int* in_sizes, int n_in,
                              void* d_out, int out_size, void* d_ws, size_t ws_size,
                              hipStream_t stream) {
    const float* coords  = (const float*)d_in[0];
    const float* centers = (const float*)d_in[1];
    const float* zetas   = (const float*)d_in[2];
    const float* coeffs  = (const float*)d_in[3];
    const float* norm    = (const float*)d_in[4];
    const float* c2s     = (const float*)d_in[5];
    float* out = (float*)d_out;
    int n = in_sizes[0] / 3;
    int grid = (n + MT - 1) / MT;

    ushort* wsHi = (ushort*)d_ws;
    ushort* wsLo = wsHi + (size_t)KP * NCOLP;
    int*    wsMeta = (int*)(wsLo + (size_t)KP * NCOLP);
    float*  wsNorm = (float*)(wsMeta + KP);
    const size_t WS_NEED = (size_t)2 * KP * NCOLP * sizeof(ushort) + KP * 8;

    if (ws_size >= WS_NEED) {
        prep_b<<<(KP * NCOLP + 255) / 256, 256, 0, stream>>>(c2s, norm, wsHi, wsLo, wsMeta, wsNorm);
        gto_mfma<true><<<grid, 256, 0, stream>>>(coords, centers, zetas, coeffs, norm, c2s,
                                                 wsHi, wsLo, wsMeta, wsNorm, out, n);
    } else {
        gto_mfma<false><<<grid, 256, 0, stream>>>(coords, centers, zetas, coeffs, norm, c2s,
                                                  nullptr, nullptr, nullptr, nullptr, out, n);
    }
}

// Round 9
// 133.218 us; speedup vs baseline: 1.1646x; 1.1646x over previous
//
#include <hip/hip_runtime.h>

typedef unsigned int uint;
typedef unsigned short ushort;
typedef __attribute__((ext_vector_type(8))) short short8;   // 8 bf16
typedef __attribute__((ext_vector_type(4))) float f32x4;
typedef __attribute__((ext_vector_type(2))) uint uint2v;

#define NSH   100
#define NPRIM 8
#define NAOC  280
#define NAOS  260
#define NATOM 20
#define KP    288
#define NKB   9
#define MT    32            // points per block
#define NCOLP 272
#define BCH   (32 * NCOLP)  // ushorts per chunk image (8704)
#define RSQRT3 0.57735026918962576f
#define LOG2E  1.4426950408889634f
#define EPS   276           // epilogue row stride (floats)

// LDS byte offsets. Temporal aliasing:
//   [12800..20992): A double-buffers (main loop)  ALIASES  zeta/coef (radial only)
//   [0..17664):     epilogue half-tile bounce     ALIASES  rad + A bufs (after loop)
#define O_RAD   0        // 100*32*4 = 12800
#define O_AH    12800    // 2 bufs * 2048 = 4096
#define O_AL    16896    // 2 bufs * 2048 = 4096 -> 20992
#define O_ZETA  12800    // 3200 (alias under A-bufs; dead after radial)
#define O_COEF  16000    // 3200 -> 19200 (alias under A-bufs)
#define O_CEN   20992    // 20 * float4 = 320
#define O_CX    21312    // 128
#define O_CY    21440    // 128
#define O_CZ    21568    // 128
#define O_NORMF 21696    // 1152
#define O_META  22848    // 1152 -> 24000
#define POOLSZ  24000    // 6 blocks/CU (was 35328 -> 4 blocks/CU)
#define EPH    (16 * EPS * 4)   // 17664 epilogue half-tile, aliases from 0

__device__ __forceinline__ ushort bf16_rne(float x) {
    uint u = __float_as_uint(x);
    return (ushort)((u + 0x7FFFu + ((u >> 16) & 1u)) >> 16);
}
__device__ __forceinline__ float bf16_to_f(ushort h) {
    return __uint_as_float(((uint)h) << 16);
}
__device__ __forceinline__ uint cvt_pk_bf16(float a, float b) {
    uint r;
    asm("v_cvt_pk_bf16_f32 %0, %1, %2" : "=v"(r) : "v"(a), "v"(b));
    return r;
}

__device__ __forceinline__ int calc_meta(int k, float& anorm) {
    int shell = 0, atom = 0, s1 = 0, s2 = 0;
    anorm = 1.0f;
    if (k < 40) {
        atom = k >> 1; shell = 5 * atom + (k & 1);
    } else if (k < 160) {
        int i = k - 40; int ip = i / 3; int c = i - 3 * ip;
        atom = ip >> 1; shell = 5 * atom + 2 + (ip & 1); s1 = 1 + c;
    } else if (k < NAOC) {
        int i = k - 160; atom = i / 6; shell = 5 * atom + 4; int c = i - 6 * atom;
        if      (c == 0) { s1 = 1; s2 = 1; }
        else if (c == 1) { s1 = 1; s2 = 2; }
        else if (c == 2) { s1 = 1; s2 = 3; }
        else if (c == 3) { s1 = 2; s2 = 2; }
        else if (c == 4) { s1 = 2; s2 = 3; }
        else             { s1 = 3; s2 = 3; }
        if (c == 0 || c == 3 || c == 5) anorm = RSQRT3;
    }
    return shell | (atom << 7) | (s1 << 12) | (s2 << 14);
}

// ---- prep: split cart2sph to bf16 hi/lo frag image + meta/normf tables ----
__global__ void prep_b(const float* __restrict__ c2s, const float* __restrict__ norm,
                       ushort* __restrict__ wsHi, ushort* __restrict__ wsLo,
                       int* __restrict__ wsMeta, float* __restrict__ wsNorm) {
    if (blockIdx.x == 0) {
        for (int k = threadIdx.x; k < KP; k += 256) {
            float an;
            int m = calc_meta(k, an);
            wsMeta[k] = m;
            wsNorm[k] = (k < NAOC ? norm[k] : 0.0f) * an;
        }
    }
    int id = blockIdx.x * 256 + threadIdx.x;
    if (id >= KP * NCOLP) return;
    int k = id / NCOLP, col = id % NCOLP;
    float v = (k < NAOC && col < NAOS) ? c2s[k * NAOS + col] : 0.0f;
    ushort hi = bf16_rne(v);
    ushort lo = bf16_rne(v - bf16_to_f(hi));
    int off = (k >> 5) * BCH +
              (((col >> 4) * 4 + ((k & 31) >> 3)) * 16 + (col & 15)) * 8 + (k & 7);
    wsHi[off] = hi;
    wsLo[off] = lo;
}

template <bool USEWS>
__global__ __launch_bounds__(256, 6) void gto_mfma(
    const float* __restrict__ coords, const float* __restrict__ centers,
    const float* __restrict__ zetas, const float* __restrict__ coeffs,
    const float* __restrict__ norm, const float* __restrict__ c2s,
    const ushort* __restrict__ wsHi, const ushort* __restrict__ wsLo,
    const int* __restrict__ wsMeta, const float* __restrict__ wsNorm,
    float* __restrict__ out, int n)
{
    __shared__ __align__(16) char smem[POOLSZ];
    float*  sRad  = (float*)(smem + O_RAD);
    float*  sZeta = (float*)(smem + O_ZETA);   // aliases A-buf region (radial only)
    float*  sCoef = (float*)(smem + O_COEF);   // aliases A-buf region (radial only)
    float4* sCen4 = (float4*)(smem + O_CEN);
    float*  sCx   = (float*)(smem + O_CX);
    float*  sCy   = (float*)(smem + O_CY);
    float*  sCz   = (float*)(smem + O_CZ);
    float*  sNormF= (float*)(smem + O_NORMF);
    int*    sMeta = (int*)(smem + O_META);

    const int t = threadIdx.x, lane = t & 63, w = t >> 6;
    const int lr = lane & 15, lg4 = lane >> 4;
    const int P0 = blockIdx.x * MT;

    // ---- stage constants ----
    for (int i = t; i < NSH * NPRIM; i += 256) {
        sZeta[i] = zetas[i] * LOG2E;           // pre-fold log2e for v_exp_f32
        sCoef[i] = coeffs[i];
    }
    if (t < NATOM)
        sCen4[t] = make_float4(centers[3 * t], centers[3 * t + 1], centers[3 * t + 2], 0.0f);
    if (t < MT * 3) {
        int gi = P0 * 3 + t;
        float v = (gi < 3 * n) ? coords[gi] : 0.0f;
        int p = t / 3, c = t - 3 * (t / 3);
        if (c == 0) sCx[p] = v; else if (c == 1) sCy[p] = v; else sCz[p] = v;
    }
    if (USEWS) {
        for (int i = t; i < KP; i += 256) { sMeta[i] = wsMeta[i]; sNormF[i] = wsNorm[i]; }
    } else {
        for (int k = t; k < KP; k += 256) {
            float an;
            sMeta[k] = calc_meta(k, an);
            sNormF[k] = (k < NAOC ? norm[k] : 0.0f) * an;
        }
    }
    __syncthreads();

    // ---- radial table rad[shell][point] (reads zeta/coef; last use of alias) ----
    #pragma unroll 1
    for (int it = 0; it < (NSH * MT + 255) / 256; ++it) {
        int id = it * 256 + t;
        if (id < NSH * MT) {
            int s = id >> 5, p = id & 31;
            int a = s / 5;
            float4 ca = sCen4[a];
            float dx = sCx[p] - ca.x;
            float dy = sCy[p] - ca.y;
            float dz = sCz[p] - ca.z;
            float r2 = dx * dx + dy * dy + dz * dz;
            float4 z0 = *(const float4*)&sZeta[s * NPRIM];
            float4 z1 = *(const float4*)&sZeta[s * NPRIM + 4];
            float4 c0 = *(const float4*)&sCoef[s * NPRIM];
            float4 c1 = *(const float4*)&sCoef[s * NPRIM + 4];
            float rad = c0.x * __builtin_amdgcn_exp2f(-z0.x * r2);
            rad += c0.y * __builtin_amdgcn_exp2f(-z0.y * r2);
            rad += c0.z * __builtin_amdgcn_exp2f(-z0.z * r2);
            rad += c0.w * __builtin_amdgcn_exp2f(-z0.w * r2);
            rad += c1.x * __builtin_amdgcn_exp2f(-z1.x * r2);
            rad += c1.y * __builtin_amdgcn_exp2f(-z1.y * r2);
            rad += c1.z * __builtin_amdgcn_exp2f(-z1.z * r2);
            rad += c1.w * __builtin_amdgcn_exp2f(-z1.w * r2);
            sRad[s * MT + p] = rad;
        }
    }

    // ---- A-build: thread (kg = t>>5, pA = t&31) -> 4 consecutive k's ----
    const int pA = t & 31, kg = t >> 5;
    auto buildA = [&](int kb2) {
        const float cxp = sCx[pA], cyp = sCy[pA], czp = sCz[pA];
        const int k0 = kb2 * 32 + kg * 4;
        int4   m4  = *(const int4*)&sMeta[k0];
        float4 nf4 = *(const float4*)&sNormF[k0];
        float v[4];
        const int   mk[4] = {m4.x, m4.y, m4.z, m4.w};
        const float nf[4] = {nf4.x, nf4.y, nf4.z, nf4.w};
        #pragma unroll
        for (int j = 0; j < 4; ++j) {
            int meta = mk[j];
            int s = meta & 127, a = (meta >> 7) & 31;
            int s1 = (meta >> 12) & 3, s2 = (meta >> 14) & 3;
            float4 ca = sCen4[a];
            float dx = cxp - ca.x, dy = cyp - ca.y, dz = czp - ca.z;
            float m1 = (s1 == 0) ? 1.0f : ((s1 == 1) ? dx : ((s1 == 2) ? dy : dz));
            float m2 = (s2 == 0) ? 1.0f : ((s2 == 1) ? dx : ((s2 == 2) ? dy : dz));
            v[j] = sRad[s * MT + pA] * (m1 * m2) * nf[j];
        }
        uint h01 = cvt_pk_bf16(v[0], v[1]);
        uint h23 = cvt_pk_bf16(v[2], v[3]);
        float r0 = v[0] - __uint_as_float(h01 << 16);
        float r1 = v[1] - __uint_as_float(h01 & 0xffff0000u);
        float r2 = v[2] - __uint_as_float(h23 << 16);
        float r3 = v[3] - __uint_as_float(h23 & 0xffff0000u);
        uint l01 = cvt_pk_bf16(r0, r1);
        uint l23 = cvt_pk_bf16(r2, r3);
        const int boff = (kb2 & 1) * 2048 + ((kg >> 1) * 512 + pA * 16 + (kg & 1) * 8);
        *(uint2v*)(smem + O_AH + boff) = (uint2v){h01, h23};
        *(uint2v*)(smem + O_AL + boff) = (uint2v){l01, l23};
    };

    __syncthreads();   // sRad ready; zeta/coef reads done -> A-bufs may clobber alias
    buildA(0);

    f32x4 acc[5][2];
    #pragma unroll
    for (int i = 0; i < 5; ++i)
        #pragma unroll
        for (int mt = 0; mt < 2; ++mt)
            acc[i][mt] = (f32x4){0.0f, 0.0f, 0.0f, 0.0f};

    for (int kb = 0; kb < NKB; ++kb) {
        __syncthreads();   // A(kb) ds_writes visible

        // A frags from buf kb&1
        short8 aH[2], aL[2];
        #pragma unroll
        for (int mt = 0; mt < 2; ++mt) {
            int off = (kb & 1) * 2048 + (lg4 * 32 + mt * 16 + lr) * 16;
            aH[mt] = *(const short8*)(smem + O_AH + off);
            aL[mt] = *(const short8*)(smem + O_AL + off);
        }

        // build next chunk's A into the other buffer (VALU fills load/MFMA shadows)
        if (kb + 1 < NKB) buildA(kb + 1);

        // MFMAs with B at point of use (L2-resident frag image; compiler hoists)
        #pragma unroll
        for (int i = 0; i < 5; ++i) {
            if (i < 4 || w == 0) {
                int nt = (i == 4) ? 16 : (w * 4 + i);
                short8 bh, bl;
                if (USEWS) {
                    bh = *(const short8*)(wsHi + (size_t)kb * BCH + (nt * 64 + lane) * 8);
                    bl = *(const short8*)(wsLo + (size_t)kb * BCH + (nt * 64 + lane) * 8);
                } else {
                    #pragma unroll
                    for (int j = 0; j < 8; ++j) {
                        int k = kb * 32 + lg4 * 8 + j;
                        int col = nt * 16 + lr;
                        float v = (k < NAOC && col < NAOS) ? c2s[k * NAOS + col] : 0.0f;
                        ushort hi = bf16_rne(v);
                        bh[j] = (short)hi;
                        bl[j] = (short)bf16_rne(v - bf16_to_f(hi));
                    }
                }
                #pragma unroll
                for (int mt = 0; mt < 2; ++mt)
                    acc[i][mt] = __builtin_amdgcn_mfma_f32_16x16x32_bf16(aH[mt], bh, acc[i][mt], 0, 0, 0);
                #pragma unroll
                for (int mt = 0; mt < 2; ++mt)
                    acc[i][mt] = __builtin_amdgcn_mfma_f32_16x16x32_bf16(aH[mt], bl, acc[i][mt], 0, 0, 0);
                #pragma unroll
                for (int mt = 0; mt < 2; ++mt)
                    acc[i][mt] = __builtin_amdgcn_mfma_f32_16x16x32_bf16(aL[mt], bh, acc[i][mt], 0, 0, 0);
            }
        }
    }

    // ---- epilogue: two half-tiles (16 rows each) through a 17.7KB bounce ----
    float* ep = (float*)smem;
    #pragma unroll
    for (int mt = 0; mt < 2; ++mt) {
        __syncthreads();   // previous contents (rad/A-bufs or prior half) consumed
        #pragma unroll
        for (int i = 0; i < 5; ++i) {
            if (i < 4 || w == 0) {
                int nt = (i == 4) ? 16 : (w * 4 + i);
                int col = nt * 16 + lr;
                #pragma unroll
                for (int r = 0; r < 4; ++r)
                    ep[(lg4 * 4 + r) * EPS + col] = acc[i][mt][r];
            }
        }
        __syncthreads();
        // rows of this half: global row = mt*16 + local (0..15)
        #pragma unroll
        for (int j = 0; j < 4; ++j) {
            int row = w + j * 4;
            int P = P0 + mt * 16 + row;
            if (P < n)
                *(float4*)&out[(size_t)P * NAOS + lane * 4] = *(const float4*)&ep[row * EPS + lane * 4];
        }
        if (w == 1 && lane < 16) {
            int P = P0 + mt * 16 + lane;
            if (P < n)
                *(float4*)&out[(size_t)P * NAOS + 256] = *(const float4*)&ep[lane * EPS + 256];
        }
    }
}

extern "C" void kernel_launch(void* const* d_in, const int* in_sizes, int n_in,
                              void* d_out, int out_size, void* d_ws, size_t ws_size,
                              hipStream_t stream) {
    const float* coords  = (const float*)d_in[0];
    const float* centers = (const float*)d_in[1];
    const float* zetas   = (const float*)d_in[2];
    const float* coeffs  = (const float*)d_in[3];
    const float* norm    = (const float*)d_in[4];
    const float* c2s     = (const float*)d_in[5];
    float* out = (float*)d_out;
    int n = in_sizes[0] / 3;
    int grid = (n + MT - 1) / MT;

    ushort* wsHi = (ushort*)d_ws;
    ushort* wsLo = wsHi + (size_t)KP * NCOLP;
    int*    wsMeta = (int*)(wsLo + (size_t)KP * NCOLP);
    float*  wsNorm = (float*)(wsMeta + KP);
    const size_t WS_NEED = (size_t)2 * KP * NCOLP * sizeof(ushort) + KP * 8;

    if (ws_size >= WS_NEED) {
        prep_b<<<(KP * NCOLP + 255) / 256, 256, 0, stream>>>(c2s, norm, wsHi, wsLo, wsMeta, wsNorm);
        gto_mfma<true><<<grid, 256, 0, stream>>>(coords, centers, zetas, coeffs, norm, c2s,
                                                 wsHi, wsLo, wsMeta, wsNorm, out, n);
    } else {
        gto_mfma<false><<<grid, 256, 0, stream>>>(coords, centers, zetas, coeffs, norm, c2s,
                                                  nullptr, nullptr, nullptr, nullptr, out, n);
    }
}

// Round 10
// 104.335 us; speedup vs baseline: 1.4870x; 1.2768x over previous
//
#include <hip/hip_runtime.h>

typedef unsigned int uint;
typedef unsigned short ushort;
typedef __attribute__((ext_vector_type(8))) short short8;   // 8 bf16
typedef __attribute__((ext_vector_type(4))) float f32x4;
typedef __attribute__((ext_vector_type(2))) uint uint2v;

#define NSH   100
#define NPRIM 8
#define NAOC  280
#define NAOS  260
#define NATOM 20
#define KP    288
#define NKB   9
#define MT    32            // points per block
#define NCOLP 272
#define BCH   (32 * NCOLP)  // ushorts per chunk image (8704)
#define RSQRT3 0.57735026918962576f
#define LOG2E  1.4426950408889634f
#define EPS   276           // epilogue row stride (floats)

// LDS byte offsets. Temporal aliasing:
//   [12800..20992): A double-buffers (main loop)  ALIASES  zeta/coef (radial only)
//   [0..17664):     epilogue half-tile bounce     ALIASES  rad + A bufs (after loop)
#define O_RAD   0        // 100*32*4 = 12800
#define O_AH    12800    // 2 bufs * 2048 = 4096
#define O_AL    16896    // 2 bufs * 2048 = 4096 -> 20992
#define O_ZETA  12800    // 3200 (alias under A-bufs; dead after radial)
#define O_COEF  16000    // 3200 -> 19200 (alias under A-bufs)
#define O_CEN   20992    // 20 * float4 = 320
#define O_CX    21312    // 128
#define O_CY    21440    // 128
#define O_CZ    21568    // 128
#define O_NORMF 21696    // 1152
#define O_META  22848    // 1152 -> 24000
#define POOLSZ  24000    // 6 blocks/CU via LDS; VGPR must stay ~64 (no cap abuse)

__device__ __forceinline__ ushort bf16_rne(float x) {
    uint u = __float_as_uint(x);
    return (ushort)((u + 0x7FFFu + ((u >> 16) & 1u)) >> 16);
}
__device__ __forceinline__ float bf16_to_f(ushort h) {
    return __uint_as_float(((uint)h) << 16);
}
__device__ __forceinline__ uint cvt_pk_bf16(float a, float b) {
    uint r;
    asm("v_cvt_pk_bf16_f32 %0, %1, %2" : "=v"(r) : "v"(a), "v"(b));
    return r;
}

__device__ __forceinline__ int calc_meta(int k, float& anorm) {
    int shell = 0, atom = 0, s1 = 0, s2 = 0;
    anorm = 1.0f;
    if (k < 40) {
        atom = k >> 1; shell = 5 * atom + (k & 1);
    } else if (k < 160) {
        int i = k - 40; int ip = i / 3; int c = i - 3 * ip;
        atom = ip >> 1; shell = 5 * atom + 2 + (ip & 1); s1 = 1 + c;
    } else if (k < NAOC) {
        int i = k - 160; atom = i / 6; shell = 5 * atom + 4; int c = i - 6 * atom;
        if      (c == 0) { s1 = 1; s2 = 1; }
        else if (c == 1) { s1 = 1; s2 = 2; }
        else if (c == 2) { s1 = 1; s2 = 3; }
        else if (c == 3) { s1 = 2; s2 = 2; }
        else if (c == 4) { s1 = 2; s2 = 3; }
        else             { s1 = 3; s2 = 3; }
        if (c == 0 || c == 3 || c == 5) anorm = RSQRT3;
    }
    return shell | (atom << 7) | (s1 << 12) | (s2 << 14);
}

// ---- prep: split cart2sph to bf16 hi/lo frag image + meta/normf tables ----
__global__ void prep_b(const float* __restrict__ c2s, const float* __restrict__ norm,
                       ushort* __restrict__ wsHi, ushort* __restrict__ wsLo,
                       int* __restrict__ wsMeta, float* __restrict__ wsNorm) {
    if (blockIdx.x == 0) {
        for (int k = threadIdx.x; k < KP; k += 256) {
            float an;
            int m = calc_meta(k, an);
            wsMeta[k] = m;
            wsNorm[k] = (k < NAOC ? norm[k] : 0.0f) * an;
        }
    }
    int id = blockIdx.x * 256 + threadIdx.x;
    if (id >= KP * NCOLP) return;
    int k = id / NCOLP, col = id % NCOLP;
    float v = (k < NAOC && col < NAOS) ? c2s[k * NAOS + col] : 0.0f;
    ushort hi = bf16_rne(v);
    ushort lo = bf16_rne(v - bf16_to_f(hi));
    int off = (k >> 5) * BCH +
              (((col >> 4) * 4 + ((k & 31) >> 3)) * 16 + (col & 15)) * 8 + (k & 7);
    wsHi[off] = hi;
    wsLo[off] = lo;
}

template <bool USEWS>
__global__ __launch_bounds__(256, 4) void gto_mfma(
    const float* __restrict__ coords, const float* __restrict__ centers,
    const float* __restrict__ zetas, const float* __restrict__ coeffs,
    const float* __restrict__ norm, const float* __restrict__ c2s,
    const ushort* __restrict__ wsHi, const ushort* __restrict__ wsLo,
    const int* __restrict__ wsMeta, const float* __restrict__ wsNorm,
    float* __restrict__ out, int n)
{
    __shared__ __align__(16) char smem[POOLSZ];
    float*  sRad  = (float*)(smem + O_RAD);
    float*  sZeta = (float*)(smem + O_ZETA);   // aliases A-buf region (radial only)
    float*  sCoef = (float*)(smem + O_COEF);   // aliases A-buf region (radial only)
    float4* sCen4 = (float4*)(smem + O_CEN);
    float*  sCx   = (float*)(smem + O_CX);
    float*  sCy   = (float*)(smem + O_CY);
    float*  sCz   = (float*)(smem + O_CZ);
    float*  sNormF= (float*)(smem + O_NORMF);
    int*    sMeta = (int*)(smem + O_META);

    const int t = threadIdx.x, lane = t & 63, w = t >> 6;
    const int lr = lane & 15, lg4 = lane >> 4;
    const int P0 = blockIdx.x * MT;

    // ---- stage constants ----
    for (int i = t; i < NSH * NPRIM; i += 256) {
        sZeta[i] = zetas[i] * LOG2E;           // pre-fold log2e for v_exp_f32
        sCoef[i] = coeffs[i];
    }
    if (t < NATOM)
        sCen4[t] = make_float4(centers[3 * t], centers[3 * t + 1], centers[3 * t + 2], 0.0f);
    if (t < MT * 3) {
        int gi = P0 * 3 + t;
        float v = (gi < 3 * n) ? coords[gi] : 0.0f;
        int p = t / 3, c = t - 3 * (t / 3);
        if (c == 0) sCx[p] = v; else if (c == 1) sCy[p] = v; else sCz[p] = v;
    }
    if (USEWS) {
        for (int i = t; i < KP; i += 256) { sMeta[i] = wsMeta[i]; sNormF[i] = wsNorm[i]; }
    } else {
        for (int k = t; k < KP; k += 256) {
            float an;
            sMeta[k] = calc_meta(k, an);
            sNormF[k] = (k < NAOC ? norm[k] : 0.0f) * an;
        }
    }
    __syncthreads();

    // ---- radial table rad[shell][point] (reads zeta/coef; last use of alias) ----
    #pragma unroll 1
    for (int it = 0; it < (NSH * MT + 255) / 256; ++it) {
        int id = it * 256 + t;
        if (id < NSH * MT) {
            int s = id >> 5, p = id & 31;
            int a = s / 5;
            float4 ca = sCen4[a];
            float dx = sCx[p] - ca.x;
            float dy = sCy[p] - ca.y;
            float dz = sCz[p] - ca.z;
            float r2 = dx * dx + dy * dy + dz * dz;
            float4 z0 = *(const float4*)&sZeta[s * NPRIM];
            float4 z1 = *(const float4*)&sZeta[s * NPRIM + 4];
            float4 c0 = *(const float4*)&sCoef[s * NPRIM];
            float4 c1 = *(const float4*)&sCoef[s * NPRIM + 4];
            float rad = c0.x * __builtin_amdgcn_exp2f(-z0.x * r2);
            rad += c0.y * __builtin_amdgcn_exp2f(-z0.y * r2);
            rad += c0.z * __builtin_amdgcn_exp2f(-z0.z * r2);
            rad += c0.w * __builtin_amdgcn_exp2f(-z0.w * r2);
            rad += c1.x * __builtin_amdgcn_exp2f(-z1.x * r2);
            rad += c1.y * __builtin_amdgcn_exp2f(-z1.y * r2);
            rad += c1.z * __builtin_amdgcn_exp2f(-z1.z * r2);
            rad += c1.w * __builtin_amdgcn_exp2f(-z1.w * r2);
            sRad[s * MT + p] = rad;
        }
    }

    // ---- A-build: thread (kg = t>>5, pA = t&31) -> 4 consecutive k's ----
    const int pA = t & 31, kg = t >> 5;
    auto buildA = [&](int kb2) {
        const float cxp = sCx[pA], cyp = sCy[pA], czp = sCz[pA];
        const int k0 = kb2 * 32 + kg * 4;
        int4   m4  = *(const int4*)&sMeta[k0];
        float4 nf4 = *(const float4*)&sNormF[k0];
        float v[4];
        const int   mk[4] = {m4.x, m4.y, m4.z, m4.w};
        const float nf[4] = {nf4.x, nf4.y, nf4.z, nf4.w};
        #pragma unroll
        for (int j = 0; j < 4; ++j) {
            int meta = mk[j];
            int s = meta & 127, a = (meta >> 7) & 31;
            int s1 = (meta >> 12) & 3, s2 = (meta >> 14) & 3;
            float4 ca = sCen4[a];
            float dx = cxp - ca.x, dy = cyp - ca.y, dz = czp - ca.z;
            float m1 = (s1 == 0) ? 1.0f : ((s1 == 1) ? dx : ((s1 == 2) ? dy : dz));
            float m2 = (s2 == 0) ? 1.0f : ((s2 == 1) ? dx : ((s2 == 2) ? dy : dz));
            v[j] = sRad[s * MT + pA] * (m1 * m2) * nf[j];
        }
        uint h01 = cvt_pk_bf16(v[0], v[1]);
        uint h23 = cvt_pk_bf16(v[2], v[3]);
        float r0 = v[0] - __uint_as_float(h01 << 16);
        float r1 = v[1] - __uint_as_float(h01 & 0xffff0000u);
        float r2 = v[2] - __uint_as_float(h23 << 16);
        float r3 = v[3] - __uint_as_float(h23 & 0xffff0000u);
        uint l01 = cvt_pk_bf16(r0, r1);
        uint l23 = cvt_pk_bf16(r2, r3);
        const int boff = (kb2 & 1) * 2048 + ((kg >> 1) * 512 + pA * 16 + (kg & 1) * 8);
        *(uint2v*)(smem + O_AH + boff) = (uint2v){h01, h23};
        *(uint2v*)(smem + O_AL + boff) = (uint2v){l01, l23};
    };

    __syncthreads();   // sRad ready; zeta/coef reads done -> A-bufs may clobber alias
    buildA(0);

    f32x4 acc[5][2];
    #pragma unroll
    for (int i = 0; i < 5; ++i)
        #pragma unroll
        for (int mt = 0; mt < 2; ++mt)
            acc[i][mt] = (f32x4){0.0f, 0.0f, 0.0f, 0.0f};

    for (int kb = 0; kb < NKB; ++kb) {
        __syncthreads();   // A(kb) ds_writes visible

        // A frags from buf kb&1
        short8 aH[2], aL[2];
        #pragma unroll
        for (int mt = 0; mt < 2; ++mt) {
            int off = (kb & 1) * 2048 + (lg4 * 32 + mt * 16 + lr) * 16;
            aH[mt] = *(const short8*)(smem + O_AH + off);
            aL[mt] = *(const short8*)(smem + O_AL + off);
        }

        // build next chunk's A into the other buffer (VALU fills load/MFMA shadows)
        if (kb + 1 < NKB) buildA(kb + 1);

        // MFMAs with B at point of use (L2-resident frag image; compiler hoists)
        #pragma unroll
        for (int i = 0; i < 5; ++i) {
            if (i < 4 || w == 0) {
                int nt = (i == 4) ? 16 : (w * 4 + i);
                short8 bh, bl;
                if (USEWS) {
                    bh = *(const short8*)(wsHi + (size_t)kb * BCH + (nt * 64 + lane) * 8);
                    bl = *(const short8*)(wsLo + (size_t)kb * BCH + (nt * 64 + lane) * 8);
                } else {
                    #pragma unroll
                    for (int j = 0; j < 8; ++j) {
                        int k = kb * 32 + lg4 * 8 + j;
                        int col = nt * 16 + lr;
                        float v = (k < NAOC && col < NAOS) ? c2s[k * NAOS + col] : 0.0f;
                        ushort hi = bf16_rne(v);
                        bh[j] = (short)hi;
                        bl[j] = (short)bf16_rne(v - bf16_to_f(hi));
                    }
                }
                #pragma unroll
                for (int mt = 0; mt < 2; ++mt)
                    acc[i][mt] = __builtin_amdgcn_mfma_f32_16x16x32_bf16(aH[mt], bh, acc[i][mt], 0, 0, 0);
                #pragma unroll
                for (int mt = 0; mt < 2; ++mt)
                    acc[i][mt] = __builtin_amdgcn_mfma_f32_16x16x32_bf16(aH[mt], bl, acc[i][mt], 0, 0, 0);
                #pragma unroll
                for (int mt = 0; mt < 2; ++mt)
                    acc[i][mt] = __builtin_amdgcn_mfma_f32_16x16x32_bf16(aL[mt], bh, acc[i][mt], 0, 0, 0);
            }
        }
    }

    // ---- epilogue: two half-tiles (16 rows each) through a 17.7KB bounce ----
    float* ep = (float*)smem;
    #pragma unroll
    for (int mt = 0; mt < 2; ++mt) {
        __syncthreads();   // previous contents (rad/A-bufs or prior half) consumed
        #pragma unroll
        for (int i = 0; i < 5; ++i) {
            if (i < 4 || w == 0) {
                int nt = (i == 4) ? 16 : (w * 4 + i);
                int col = nt * 16 + lr;
                #pragma unroll
                for (int r = 0; r < 4; ++r)
                    ep[(lg4 * 4 + r) * EPS + col] = acc[i][mt][r];
            }
        }
        __syncthreads();
        // rows of this half: global row = mt*16 + local (0..15)
        #pragma unroll
        for (int j = 0; j < 4; ++j) {
            int row = w + j * 4;
            int P = P0 + mt * 16 + row;
            if (P < n)
                *(float4*)&out[(size_t)P * NAOS + lane * 4] = *(const float4*)&ep[row * EPS + lane * 4];
        }
        if (w == 1 && lane < 16) {
            int P = P0 + mt * 16 + lane;
            if (P < n)
                *(float4*)&out[(size_t)P * NAOS + 256] = *(const float4*)&ep[lane * EPS + 256];
        }
    }
}

extern "C" void kernel_launch(void* const* d_in, const int* in_sizes, int n_in,
                              void* d_out, int out_size, void* d_ws, size_t ws_size,
                              hipStream_t stream) {
    const float* coords  = (const float*)d_in[0];
    const float* centers = (const float*)d_in[1];
    const float* zetas   = (const float*)d_in[2];
    const float* coeffs  = (const float*)d_in[3];
    const float* norm    = (const float*)d_in[4];
    const float* c2s     = (const float*)d_in[5];
    float* out = (float*)d_out;
    int n = in_sizes[0] / 3;
    int grid = (n + MT - 1) / MT;

    ushort* wsHi = (ushort*)d_ws;
    ushort* wsLo = wsHi + (size_t)KP * NCOLP;
    int*    wsMeta = (int*)(wsLo + (size_t)KP * NCOLP);
    float*  wsNorm = (float*)(wsMeta + KP);
    const size_t WS_NEED = (size_t)2 * KP * NCOLP * sizeof(ushort) + KP * 8;

    if (ws_size >= WS_NEED) {
        prep_b<<<(KP * NCOLP + 255) / 256, 256, 0, stream>>>(c2s, norm, wsHi, wsLo, wsMeta, wsNorm);
        gto_mfma<true><<<grid, 256, 0, stream>>>(coords, centers, zetas, coeffs, norm, c2s,
                                                 wsHi, wsLo, wsMeta, wsNorm, out, n);
    } else {
        gto_mfma<false><<<grid, 256, 0, stream>>>(coords, centers, zetas, coeffs, norm, c2s,
                                                  nullptr, nullptr, nullptr, nullptr, out, n);
    }
}